// Round 2
// baseline (11923.886 us; speedup 1.0000x reference)
//
#include <hip/hip_runtime.h>
#include <hip/hip_bf16.h>
#include <stdint.h>

#define NT 365
#define NGRID 512
#define NX 256
#define HID 1024

typedef __bf16 bf16x8 __attribute__((ext_vector_type(8)));
typedef float f32x16 __attribute__((ext_vector_type(16)));

__device__ __forceinline__ unsigned short f2bf(float f) {
    union { float f; uint32_t u; } v; v.f = f;
    uint32_t u = v.u;
    uint32_t r = (u + 0x7FFFu + ((u >> 16) & 1u)) >> 16;
    return (unsigned short)r;
}
__device__ __forceinline__ float sigmoidf_(float x) {
    return 1.0f / (1.0f + __expf(-x));
}
__device__ __forceinline__ float tanhf_(float x) {
    return 1.0f - 2.0f / (__expf(2.0f * x) + 1.0f);
}

// ---------------- prep kernels ----------------

// WP[jg 0..127][kt 0..79][l 0..63][e 0..7] : B-frag order, gate-packed cols.
// col n = l&31 : gate = n&3, j = jg*8 + (n>>2); k = kt*16 + (l>>5)*8 + e.
__global__ void pack_w_kernel(const float* __restrict__ W_ih,
                              const float* __restrict__ W_hh,
                              unsigned short* __restrict__ WP) {
    int tid = blockIdx.x * blockDim.x + threadIdx.x;
    if (tid >= 128 * 80 * 64) return;
    int l  = tid & 63;
    int kt = (tid >> 6) % 80;
    int jg = tid / (80 * 64);
    int n = l & 31;
    int gate = n & 3;
    int j = jg * 8 + (n >> 2);
    int k = kt * 16 + ((l >> 5) << 3);
    int row = gate * HID + j;
    const float* src = (k < HID) ? (W_hh + (size_t)row * HID + k)
                                 : (W_ih + (size_t)row * NX + (k - HID));
    unsigned short* dst = WP + (size_t)tid * 8;
    #pragma unroll
    for (int e = 0; e < 8; ++e) dst[e] = f2bf(src[e]);
}

// XM[t][bi][kt 0..15][a][l][e] : A-frag order of bf16(x * maskX).
// b = bi*64 + a*32 + (l&31); n = kt*16 + (l>>5)*8 + e.
__global__ void pack_xm_kernel(const float* __restrict__ x,
                               const float* __restrict__ maskX,
                               unsigned short* __restrict__ XM) {
    size_t tid = (size_t)blockIdx.x * blockDim.x + threadIdx.x;
    if (tid >= (size_t)NT * 16384) return;
    int l  = tid & 63;
    int a  = (tid >> 6) & 1;
    int kt = (tid >> 7) & 15;
    int bi = (tid >> 11) & 7;
    int t  = tid >> 14;
    int b = bi * 64 + a * 32 + (l & 31);
    int n = kt * 16 + ((l >> 5) << 3);
    const float* xs = x + ((size_t)t * NGRID + b) * NX + n;
    const float* ms = maskX + (size_t)b * NX + n;
    unsigned short* dst = XM + tid * 8;
    #pragma unroll
    for (int e = 0; e < 8; ++e) dst[e] = f2bf(xs[e] * ms[e]);
}

// out = b_lin, barrier counters = 0
__global__ void init_kernel(float* __restrict__ out,
                            const float* __restrict__ b_lin,
                            int* __restrict__ ctr) {
    int i = blockIdx.x * blockDim.x + threadIdx.x;
    if (i < NT * NGRID) out[i] = b_lin[0];
    if (i < 8) ctr[i * 32] = 0;
}

// ---------------- persistent LSTM kernel ----------------
// 256 WGs x 256 thr. WG(bi = blk&7, wgJ = blk>>3). Wave w: jg = wgJ*4+w.
// Wave tile: 64 b-rows x 32 cols (cols = 8 j x 4 gates). W in 320 VGPRs.
__global__ __launch_bounds__(256, 1)
void lstm_persist_kernel(const unsigned short* __restrict__ WPg,
                         const unsigned short* __restrict__ XMg,
                         unsigned short* __restrict__ hA,
                         unsigned short* __restrict__ hB,
                         const float* __restrict__ b_ih,
                         const float* __restrict__ b_hh,
                         const float* __restrict__ W_lin,
                         float* __restrict__ out,
                         int* __restrict__ ctr)
{
    __shared__ float exch[4][2560];   // per-wave gate transpose, stride-5
    __shared__ float outred[4][64];

    const int tid = threadIdx.x;
    const int w = tid >> 6;
    const int l = tid & 63;
    const int bi = blockIdx.x & 7;
    const int wgJ = blockIdx.x >> 3;
    const int jg = wgJ * 4 + w;          // 0..127

    // ---- load W into registers (80 frags = 320 VGPRs) ----
    const bf16x8* __restrict__ WPv = (const bf16x8*)WPg + (size_t)jg * 5120 + l;
    bf16x8 wreg[80];
    #pragma unroll
    for (int kt = 0; kt < 80; ++kt) wreg[kt] = WPv[kt * 64];

    // ---- per-lane constants ----
    const int c = l & 31;
    const int gate = c & 3;
    const int jcol = jg * 8 + (c >> 2);
    const float bias = b_ih[gate * HID + jcol] + b_hh[gate * HID + jcol];

    const int jlane = jg * 8 + (l & 7);  // epilogue j
    const float wl = W_lin[jlane];
    const int h2 = jg & 1;
    const int ktH = jg >> 1;
    // h-store element base: frag(bi, ktH, a=r>>5), lane = h2*32 + (r&31), e = l&7
    const int sbase = (bi * 8192 + ktH * 128 + h2 * 32) * 8 + (l & 7);

    const bf16x8* __restrict__ hAv = (const bf16x8*)hA;
    const bf16x8* __restrict__ hBv = (const bf16x8*)hB;
    const bf16x8* __restrict__ XMv = (const bf16x8*)XMg;
    int* __restrict__ my_ctr = ctr + bi * 32;

    float creg[8];
    #pragma unroll
    for (int k = 0; k < 8; ++k) creg[k] = 0.0f;

    #pragma unroll 1
    for (int t = 0; t < NT; ++t) {
        f32x16 acc0 = {};
        f32x16 acc1 = {};

        // ---- xm part (no dependence on barrier) ----
        const bf16x8* __restrict__ xp = XMv + (size_t)t * 16384 + bi * 2048 + l;
        #pragma unroll
        for (int kt = 0; kt < 16; ++kt) {
            bf16x8 a0 = xp[kt * 128];
            bf16x8 a1 = xp[kt * 128 + 64];
            acc0 = __builtin_amdgcn_mfma_f32_32x32x16_bf16(a0, wreg[64 + kt], acc0, 0, 0, 0);
            acc1 = __builtin_amdgcn_mfma_f32_32x32x16_bf16(a1, wreg[64 + kt], acc1, 0, 0, 0);
        }

        // ---- wait for h(t-1) from our 32-WG group ----
        if (t > 0) {
            if (tid == 0) {
                const int target = 32 * t;
                while (__hip_atomic_load(my_ctr, __ATOMIC_ACQUIRE,
                                         __HIP_MEMORY_SCOPE_AGENT) < target) {
                    __builtin_amdgcn_s_sleep(2);
                }
            }
        }
        __syncthreads();   // broadcast barrier result; also protects outred reuse

        // ---- h part ----
        if (t > 0) {
            const bf16x8* __restrict__ hp = ((t & 1) ? hAv : hBv) + bi * 8192 + l;
            #pragma unroll
            for (int kt = 0; kt < 64; ++kt) {
                bf16x8 a0 = hp[kt * 128];
                bf16x8 a1 = hp[kt * 128 + 64];
                acc0 = __builtin_amdgcn_mfma_f32_32x32x16_bf16(a0, wreg[kt], acc0, 0, 0, 0);
                acc1 = __builtin_amdgcn_mfma_f32_32x32x16_bf16(a1, wreg[kt], acc1, 0, 0, 0);
            }
        }

        // ---- gate transpose through per-wave LDS (stride 5, conflict-light) ----
        const int jj = c >> 2;
        #pragma unroll
        for (int ri = 0; ri < 16; ++ri) {
            int r0 = (ri & 3) + 8 * (ri >> 2) + 4 * (l >> 5);
            int f0 = r0 * 8 + jj;
            exch[w][f0 * 5 + gate] = acc0[ri] + bias;
            int f1 = (r0 + 32) * 8 + jj;
            exch[w][f1 * 5 + gate] = acc1[ri] + bias;
        }
        // wave-local: ds writes then reads, no barrier needed

        unsigned short* __restrict__ hout =
            (unsigned short*)((t & 1) ? hB : hA);
        float pr[8];
        #pragma unroll
        for (int k = 0; k < 8; ++k) {
            int f = l + 64 * k;          // r = (l>>3)+8k, j = jlane
            int r = f >> 3;
            float iv = exch[w][f * 5 + 0];
            float fv = exch[w][f * 5 + 1];
            float gv = exch[w][f * 5 + 2];
            float ov = exch[w][f * 5 + 3];
            float ig = sigmoidf_(iv);
            float fg = sigmoidf_(fv);
            float gg = tanhf_(gv);
            float og = sigmoidf_(ov);
            float cn = fg * creg[k] + ig * gg;
            creg[k] = cn;
            float h = og * tanhf_(cn);
            hout[sbase + (r >> 5) * 512 + (r & 31) * 8] = f2bf(h);
            pr[k] = h * wl;
        }

        // ---- out projection: reduce over j (lanes l&7) then over 4 waves ----
        #pragma unroll
        for (int k = 0; k < 8; ++k) {
            float v = pr[k];
            v += __shfl_xor(v, 1);
            v += __shfl_xor(v, 2);
            v += __shfl_xor(v, 4);
            if ((l & 7) == 0) outred[w][(l >> 3) + 8 * k] = v;
        }
        __syncthreads();
        if (tid < 64) {
            float s = outred[0][tid] + outred[1][tid] + outred[2][tid] + outred[3][tid];
            atomicAdd(out + (size_t)t * NGRID + bi * 64 + tid, s);
        }
        if (tid == 0) {
            __threadfence();   // release h stores (wbl2) before arrive
            __hip_atomic_fetch_add(my_ctr, 1, __ATOMIC_RELEASE,
                                   __HIP_MEMORY_SCOPE_AGENT);
        }
    }
}

// ---------------- launch ----------------
extern "C" void kernel_launch(void* const* d_in, const int* in_sizes, int n_in,
                              void* d_out, int out_size, void* d_ws, size_t ws_size,
                              hipStream_t stream)
{
    const float* x     = (const float*)d_in[0];
    const float* maskX = (const float*)d_in[1];
    const float* W_ih  = (const float*)d_in[2];
    const float* W_hh  = (const float*)d_in[3];
    const float* b_ih  = (const float*)d_in[4];
    const float* b_hh  = (const float*)d_in[5];
    const float* W_lin = (const float*)d_in[6];
    const float* b_lin = (const float*)d_in[7];
    float* out = (float*)d_out;

    char* ws = (char*)d_ws;
    const size_t WP_B = 128ull * 80 * 512 * 2;           // 10,485,760
    const size_t XM_B = (size_t)NT * 16384 * 8 * 2;      // 95,682,560
    const size_t H_B  = (size_t)NGRID * HID * 2;         // 1,048,576
    unsigned short* WP = (unsigned short*)ws;
    unsigned short* XM = (unsigned short*)(ws + WP_B);
    unsigned short* hA = (unsigned short*)(ws + WP_B + XM_B);
    unsigned short* hB = (unsigned short*)(ws + WP_B + XM_B + H_B);
    int* ctr           = (int*)(ws + WP_B + XM_B + 2 * H_B);

    init_kernel<<<(NT * NGRID + 255) / 256, 256, 0, stream>>>(out, b_lin, ctr);
    pack_w_kernel<<<(128 * 80 * 64 + 255) / 256, 256, 0, stream>>>(W_ih, W_hh, WP);
    size_t nxm = (size_t)NT * 16384;
    pack_xm_kernel<<<(int)((nxm + 255) / 256), 256, 0, stream>>>(x, maskX, XM);

    lstm_persist_kernel<<<256, 256, 0, stream>>>(WP, XM, hA, hB,
                                                 b_ih, b_hh, W_lin, out, ctr);
}

// Round 3
// 6507.939 us; speedup vs baseline: 1.8322x; 1.8322x over previous
//
#include <hip/hip_runtime.h>
#include <hip/hip_bf16.h>
#include <stdint.h>

#define NT 365
#define NGRID 512
#define NX 256
#define HID 1024

typedef __bf16 bf16x8 __attribute__((ext_vector_type(8)));
typedef float f32x16 __attribute__((ext_vector_type(16)));

__device__ __forceinline__ unsigned short f2bf(float f) {
    union { float f; uint32_t u; } v; v.f = f;
    uint32_t u = v.u;
    uint32_t r = (u + 0x7FFFu + ((u >> 16) & 1u)) >> 16;
    return (unsigned short)r;
}
__device__ __forceinline__ float sigmoidf_(float x) {
    return 1.0f / (1.0f + __expf(-x));
}
__device__ __forceinline__ float tanhf_(float x) {
    return 1.0f - 2.0f / (__expf(2.0f * x) + 1.0f);
}

// ---------------- prep kernels ----------------

// WP[jg 0..127][kt 0..79][l 0..63][e 0..7] : B-frag order, gate-packed cols.
// col n = l&31 : gate = n&3, j = jg*8 + (n>>2); k = kt*16 + (l>>5)*8 + e.
__global__ void pack_w_kernel(const float* __restrict__ W_ih,
                              const float* __restrict__ W_hh,
                              unsigned short* __restrict__ WP) {
    int tid = blockIdx.x * blockDim.x + threadIdx.x;
    if (tid >= 128 * 80 * 64) return;
    int l  = tid & 63;
    int kt = (tid >> 6) % 80;
    int jg = tid / (80 * 64);
    int n = l & 31;
    int gate = n & 3;
    int j = jg * 8 + (n >> 2);
    int k = kt * 16 + ((l >> 5) << 3);
    int row = gate * HID + j;
    const float* src = (k < HID) ? (W_hh + (size_t)row * HID + k)
                                 : (W_ih + (size_t)row * NX + (k - HID));
    unsigned short* dst = WP + (size_t)tid * 8;
    #pragma unroll
    for (int e = 0; e < 8; ++e) dst[e] = f2bf(src[e]);
}

// XM[t][bi][kt 0..15][a][l][e] : A-frag order of bf16(x * maskX).
__global__ void pack_xm_kernel(const float* __restrict__ x,
                               const float* __restrict__ maskX,
                               unsigned short* __restrict__ XM) {
    size_t tid = (size_t)blockIdx.x * blockDim.x + threadIdx.x;
    if (tid >= (size_t)NT * 16384) return;
    int l  = tid & 63;
    int a  = (tid >> 6) & 1;
    int kt = (tid >> 7) & 15;
    int bi = (tid >> 11) & 7;
    int t  = tid >> 14;
    int b = bi * 64 + a * 32 + (l & 31);
    int n = kt * 16 + ((l >> 5) << 3);
    const float* xs = x + ((size_t)t * NGRID + b) * NX + n;
    const float* ms = maskX + (size_t)b * NX + n;
    unsigned short* dst = XM + tid * 8;
    #pragma unroll
    for (int e = 0; e < 8; ++e) dst[e] = f2bf(xs[e] * ms[e]);
}

__global__ void init_kernel(float* __restrict__ out,
                            const float* __restrict__ b_lin,
                            int* __restrict__ ctr) {
    int i = blockIdx.x * blockDim.x + threadIdx.x;
    if (i < NT * NGRID) out[i] = b_lin[0];
    if (i < 8) ctr[i * 32] = 0;
}

// ---------------- persistent LSTM kernel ----------------
// 256 WGs x 256 thr, 1 WG/CU. WG(bi = blk&7, wgJ = blk>>3). Wave w: jg = wgJ*4+w.
// h exchange: relaxed agent atomics (sc-bypass, NO acquire/release -> L1/L2 stay warm).
// h(t-1) staged once per CU into 64KB LDS (2x32KB ping-pong, 4 chunks of 16 kt),
// chunk i+1's L3 loads overlap chunk i's ds_read+MFMA.
__global__ __launch_bounds__(256, 1)
void lstm_persist_kernel(const unsigned short* __restrict__ WPg,
                         const unsigned short* __restrict__ XMg,
                         unsigned int* __restrict__ hA,
                         unsigned int* __restrict__ hB,
                         const float* __restrict__ b_ih,
                         const float* __restrict__ b_hh,
                         const float* __restrict__ W_lin,
                         float* __restrict__ out,
                         int* __restrict__ ctr)
{
    __shared__ unsigned long long hsm[8192];   // 64 KB: staging; exch/outred overlaid
    float* exch = (float*)hsm;                 // 4 x 2560 floats = 40 KB
    float* outred = (float*)hsm + 10240;       // 256 floats at 40 KB

    const int tid = threadIdx.x;
    const int w = tid >> 6;
    const int l = tid & 63;
    const int bi = blockIdx.x & 7;
    const int wgJ = blockIdx.x >> 3;
    const int jg = wgJ * 4 + w;

    // W h-part (kt 0..63) resident in 256 regs; xm-part streamed from L2.
    const bf16x8* __restrict__ WPv = (const bf16x8*)WPg + (size_t)jg * 5120 + l;
    bf16x8 wreg[64];
    #pragma unroll
    for (int kt = 0; kt < 64; ++kt) wreg[kt] = WPv[kt * 64];
    const bf16x8* __restrict__ WPx = WPv + 64 * 64;

    const int c = l & 31;
    const int gate = c & 3;
    const int jcol = jg * 8 + (c >> 2);
    const float bias = b_ih[gate * HID + jcol] + b_hh[gate * HID + jcol];

    // cell-update mapping: lane l -> j-pair p = l&3 (j = jg*8+2p,+1), rl = l>>2
    const int p = l & 3;
    const int rl = l >> 2;
    const float wl0 = W_lin[jg * 8 + 2 * p];
    const float wl1 = W_lin[jg * 8 + 2 * p + 1];

    const bf16x8* __restrict__ XMv = (const bf16x8*)XMg;
    int* __restrict__ my_ctr = ctr + bi * 32;

    float creg[8];
    #pragma unroll
    for (int k = 0; k < 8; ++k) creg[k] = 0.0f;

    #pragma unroll 1
    for (int t = 0; t < NT; ++t) {
        f32x16 acc0 = {};
        f32x16 acc1 = {};

        // ---- xm part: normal cached loads, no flag dependency ----
        const bf16x8* __restrict__ xp = XMv + (size_t)t * 16384 + bi * 2048 + l;
        #pragma unroll
        for (int kt = 0; kt < 16; ++kt) {
            bf16x8 bfr = WPx[kt * 64];
            acc0 = __builtin_amdgcn_mfma_f32_32x32x16_bf16(xp[kt * 128],      bfr, acc0, 0, 0, 0);
            acc1 = __builtin_amdgcn_mfma_f32_32x32x16_bf16(xp[kt * 128 + 64], bfr, acc1, 0, 0, 0);
        }

        // ---- wait for h(t-1): relaxed spin, no acquire fence ----
        if (t > 0 && tid == 0) {
            const int target = 32 * t;
            while (__hip_atomic_load(my_ctr, __ATOMIC_RELAXED,
                                     __HIP_MEMORY_SCOPE_AGENT) < target) {
                __builtin_amdgcn_s_sleep(2);
            }
        }
        __syncthreads();   // (c) broadcast; also orders prev-step exch/outred reads

        if (t > 0) {
            __asm__ volatile("" ::: "memory");
            const unsigned long long* __restrict__ hr =
                (const unsigned long long*)((t & 1) ? hA : hB) + (size_t)bi * 16384 + tid;

            // chunk 0 -> region 0
            unsigned long long stg[16];
            #pragma unroll
            for (int ch = 0; ch < 16; ++ch)
                stg[ch] = __hip_atomic_load(hr + ch * 256, __ATOMIC_RELAXED,
                                            __HIP_MEMORY_SCOPE_AGENT);
            #pragma unroll
            for (int ch = 0; ch < 16; ++ch) hsm[ch * 256 + tid] = stg[ch];
            __syncthreads();

            // pipeline: prefetch chunk ci+1 while MFMA-ing chunk ci
            #pragma unroll
            for (int ci = 0; ci < 4; ++ci) {
                if (ci < 3) {
                    #pragma unroll
                    for (int ch = 0; ch < 16; ++ch)
                        stg[ch] = __hip_atomic_load(hr + (ci + 1) * 4096 + ch * 256,
                                                    __ATOMIC_RELAXED,
                                                    __HIP_MEMORY_SCOPE_AGENT);
                }
                const bf16x8* __restrict__ hls = (const bf16x8*)(hsm + (ci & 1) * 4096);
                #pragma unroll
                for (int kt = 0; kt < 16; ++kt) {
                    int ktg = ci * 16 + kt;
                    acc0 = __builtin_amdgcn_mfma_f32_32x32x16_bf16(hls[kt * 128 + l],      wreg[ktg], acc0, 0, 0, 0);
                    acc1 = __builtin_amdgcn_mfma_f32_32x32x16_bf16(hls[kt * 128 + 64 + l], wreg[ktg], acc1, 0, 0, 0);
                }
                if (ci < 3) {
                    unsigned long long* __restrict__ dst = hsm + ((ci + 1) & 1) * 4096;
                    #pragma unroll
                    for (int ch = 0; ch < 16; ++ch) dst[ch * 256 + tid] = stg[ch];
                }
                __syncthreads();
            }
        }

        // ---- gate transpose through per-wave LDS (exch overlays staging) ----
        const int jj = c >> 2;
        const int wb = w * 2560;
        #pragma unroll
        for (int ri = 0; ri < 16; ++ri) {
            int r0 = (ri & 3) + 8 * (ri >> 2) + 4 * (l >> 5);
            exch[wb + (r0 * 8 + jj) * 5 + gate]        = acc0[ri] + bias;
            exch[wb + ((r0 + 32) * 8 + jj) * 5 + gate] = acc1[ri] + bias;
        }
        // wave-local write->read; compiler inserts lgkmcnt waits

        unsigned int* __restrict__ hw =
            ((t & 1) ? hB : hA) + (size_t)bi * 32768 + (jg >> 1) * 512 + p;
        float pr[4];
        #pragma unroll
        for (int k = 0; k < 4; ++k) {
            int r = rl + 16 * k;
            int f0 = wb + (r * 8 + 2 * p) * 5;
            float ia = sigmoidf_(exch[f0 + 0]);
            float fa = sigmoidf_(exch[f0 + 1]);
            float ga = tanhf_(exch[f0 + 2]);
            float oa = sigmoidf_(exch[f0 + 3]);
            float ib = sigmoidf_(exch[f0 + 5]);
            float fb = sigmoidf_(exch[f0 + 6]);
            float gb = tanhf_(exch[f0 + 7]);
            float ob = sigmoidf_(exch[f0 + 8]);
            float c0 = fa * creg[2 * k] + ia * ga;     creg[2 * k] = c0;
            float c1 = fb * creg[2 * k + 1] + ib * gb; creg[2 * k + 1] = c1;
            float h0 = oa * tanhf_(c0);
            float h1 = ob * tanhf_(c1);
            unsigned int pk = (unsigned int)f2bf(h0) | ((unsigned int)f2bf(h1) << 16);
            int a = r >> 5;
            int flane = ((jg & 1) << 5) | (r & 31);
            __hip_atomic_store(&hw[a * 256 + flane * 4], pk, __ATOMIC_RELAXED,
                               __HIP_MEMORY_SCOPE_AGENT);
            pr[k] = h0 * wl0 + h1 * wl1;
        }

        // ---- out projection: reduce over j-pairs then waves ----
        #pragma unroll
        for (int k = 0; k < 4; ++k) {
            float v = pr[k];
            v += __shfl_xor(v, 1);
            v += __shfl_xor(v, 2);
            if (p == 0) outred[w * 64 + rl + 16 * k] = v;
        }

        // drain this wave's h stores (every wave) before the barrier, so the
        // flag add below is ordered after ALL h stores reached the MALL.
        __builtin_amdgcn_s_waitcnt(0);
        __syncthreads();   // (b)

        if (tid < 64) {
            float s = outred[tid] + outred[64 + tid] + outred[128 + tid] + outred[192 + tid];
            atomicAdd(out + (size_t)t * NGRID + bi * 64 + tid, s);
        }
        if (tid == 0) {
            __asm__ volatile("" ::: "memory");
            __hip_atomic_fetch_add(my_ctr, 1, __ATOMIC_RELAXED,
                                   __HIP_MEMORY_SCOPE_AGENT);
        }
    }
}

// ---------------- launch ----------------
extern "C" void kernel_launch(void* const* d_in, const int* in_sizes, int n_in,
                              void* d_out, int out_size, void* d_ws, size_t ws_size,
                              hipStream_t stream)
{
    const float* x     = (const float*)d_in[0];
    const float* maskX = (const float*)d_in[1];
    const float* W_ih  = (const float*)d_in[2];
    const float* W_hh  = (const float*)d_in[3];
    const float* b_ih  = (const float*)d_in[4];
    const float* b_hh  = (const float*)d_in[5];
    const float* W_lin = (const float*)d_in[6];
    const float* b_lin = (const float*)d_in[7];
    float* out = (float*)d_out;

    char* ws = (char*)d_ws;
    const size_t WP_B = 128ull * 80 * 512 * 2;           // 10,485,760
    const size_t XM_B = (size_t)NT * 16384 * 8 * 2;      // 95,682,560
    const size_t H_B  = (size_t)NGRID * HID * 2;         // 1,048,576
    unsigned short* WP = (unsigned short*)ws;
    unsigned short* XM = (unsigned short*)(ws + WP_B);
    unsigned int* hA   = (unsigned int*)(ws + WP_B + XM_B);
    unsigned int* hB   = (unsigned int*)(ws + WP_B + XM_B + H_B);
    int* ctr           = (int*)(ws + WP_B + XM_B + 2 * H_B);

    init_kernel<<<(NT * NGRID + 255) / 256, 256, 0, stream>>>(out, b_lin, ctr);
    pack_w_kernel<<<(128 * 80 * 64 + 255) / 256, 256, 0, stream>>>(W_ih, W_hh, WP);
    size_t nxm = (size_t)NT * 16384;
    pack_xm_kernel<<<(int)((nxm + 255) / 256), 256, 0, stream>>>(x, maskX, XM);

    lstm_persist_kernel<<<256, 256, 0, stream>>>(WP, XM, hA, hB,
                                                 b_ih, b_hh, W_lin, out, ctr);
}

// Round 5
// 6263.671 us; speedup vs baseline: 1.9037x; 1.0390x over previous
//
#include <hip/hip_runtime.h>
#include <hip/hip_bf16.h>
#include <stdint.h>

#define NT 365
#define NGRID 512
#define NX 256
#define HID 1024

typedef __bf16 bf16x8 __attribute__((ext_vector_type(8)));
typedef float f32x16 __attribute__((ext_vector_type(16)));
typedef int   i32x4  __attribute__((ext_vector_type(4)));

__device__ __forceinline__ unsigned short f2bf(float f) {
    union { float f; uint32_t u; } v; v.f = f;
    uint32_t u = v.u;
    uint32_t r = (u + 0x7FFFu + ((u >> 16) & 1u)) >> 16;
    return (unsigned short)r;
}
__device__ __forceinline__ float sigmoidf_(float x) {
    return 1.0f / (1.0f + __expf(-x));
}
__device__ __forceinline__ float tanhf_(float x) {
    return 1.0f - 2.0f / (__expf(2.0f * x) + 1.0f);
}
__device__ __forceinline__ f32x16 mfma(bf16x8 a, bf16x8 b, f32x16 c) {
    return __builtin_amdgcn_mfma_f32_32x32x16_bf16(a, b, c, 0, 0, 0);
}

// ---------------- prep kernels ----------------

// WP[jg 0..127][kt 0..79][l 0..63][e 0..7] : B-frag order, gate-packed cols.
__global__ void pack_w_kernel(const float* __restrict__ W_ih,
                              const float* __restrict__ W_hh,
                              unsigned short* __restrict__ WP) {
    int tid = blockIdx.x * blockDim.x + threadIdx.x;
    if (tid >= 128 * 80 * 64) return;
    int l  = tid & 63;
    int kt = (tid >> 6) % 80;
    int jg = tid / (80 * 64);
    int n = l & 31;
    int gate = n & 3;
    int j = jg * 8 + (n >> 2);
    int k = kt * 16 + ((l >> 5) << 3);
    int row = gate * HID + j;
    const float* src = (k < HID) ? (W_hh + (size_t)row * HID + k)
                                 : (W_ih + (size_t)row * NX + (k - HID));
    unsigned short* dst = WP + (size_t)tid * 8;
    #pragma unroll
    for (int e = 0; e < 8; ++e) dst[e] = f2bf(src[e]);
}

// XM[t][bi][kt 0..15][a][l][e] : A-frag order of bf16(x * maskX).
__global__ void pack_xm_kernel(const float* __restrict__ x,
                               const float* __restrict__ maskX,
                               unsigned short* __restrict__ XM) {
    size_t tid = (size_t)blockIdx.x * blockDim.x + threadIdx.x;
    if (tid >= (size_t)NT * 16384) return;
    int l  = tid & 63;
    int a  = (tid >> 6) & 1;
    int kt = (tid >> 7) & 15;
    int bi = (tid >> 11) & 7;
    int t  = tid >> 14;
    int b = bi * 64 + a * 32 + (l & 31);
    int n = kt * 16 + ((l >> 5) << 3);
    const float* xs = x + ((size_t)t * NGRID + b) * NX + n;
    const float* ms = maskX + (size_t)b * NX + n;
    unsigned short* dst = XM + tid * 8;
    #pragma unroll
    for (int e = 0; e < 8; ++e) dst[e] = f2bf(xs[e] * ms[e]);
}

__global__ void init_kernel(float* __restrict__ out,
                            const float* __restrict__ b_lin,
                            int* __restrict__ ctr, int prefill) {
    int i = blockIdx.x * blockDim.x + threadIdx.x;
    if (i < 1024) ctr[i] = 0;
    if (prefill && i < NT * NGRID) out[i] = b_lin[0];
}

// final reduction: out[t,b] = b_lin + sum_wgJ OPart[t][bi][wgJ][bl]
__global__ void reduce_out_kernel(const float* __restrict__ OPart,
                                  const float* __restrict__ b_lin,
                                  float* __restrict__ out) {
    int i = blockIdx.x * blockDim.x + threadIdx.x;
    if (i >= NT * NGRID) return;
    int t = i >> 9, b = i & 511;
    int bi = b >> 6, bl = b & 63;
    const float* p = OPart + ((size_t)(t * 8 + bi) * 32) * 64 + bl;
    float s = b_lin[0];
    #pragma unroll
    for (int g = 0; g < 32; ++g) s += p[g * 64];
    out[i] = s;
}

// ---------------- persistent LSTM loop (templated on exchange scope) ----------------
// BAL=true : all 32 group members verified on one XCD -> L2-scope exchange
//            (plain write-through stores, sc0 loads, workgroup-scope flag RMW).
// BAL=false: round-3 MALL path (agent relaxed atomics).
template<bool BAL>
__device__ void lstm_loop(int tid, int bi, int wgJ,
                          const unsigned short* __restrict__ WPg,
                          const unsigned short* __restrict__ XMg,
                          unsigned int* __restrict__ hA,
                          unsigned int* __restrict__ hB,
                          const float* __restrict__ b_ih,
                          const float* __restrict__ b_hh,
                          const float* __restrict__ W_lin,
                          float* __restrict__ out,
                          float* __restrict__ OPart,
                          int* __restrict__ flag,
                          i32x4* hsm4)
{
    const int w = tid >> 6;
    const int l = tid & 63;
    const int jg = wgJ * 4 + w;

    float* exch = (float*)hsm4;                 // 4 x 2560 floats (overlay)
    float* outred = (float*)hsm4 + 10240;       // 256 floats (overlay)
    unsigned long long* hsm = (unsigned long long*)hsm4;

    // W h-part resident; xm-part streamed from L2
    const bf16x8* __restrict__ WPv = (const bf16x8*)WPg + (size_t)jg * 5120 + l;
    bf16x8 wreg[64];
    #pragma unroll
    for (int kt = 0; kt < 64; ++kt) wreg[kt] = WPv[kt * 64];
    const bf16x8* __restrict__ WPx = WPv + 64 * 64;

    const int c = l & 31;
    const int gate = c & 3;
    const int jcol = jg * 8 + (c >> 2);
    const float bias = b_ih[gate * HID + jcol] + b_hh[gate * HID + jcol];

    const int p = l & 3;
    const int rl = l >> 2;
    const float wl0 = W_lin[jg * 8 + 2 * p];
    const float wl1 = W_lin[jg * 8 + 2 * p + 1];

    const bf16x8* __restrict__ XMv = (const bf16x8*)XMg;
    const int voff = tid * 16;

    float creg[8];
    #pragma unroll
    for (int k = 0; k < 8; ++k) creg[k] = 0.0f;

    f32x16 acc0, acc1;

    auto issue = [&](i32x4* stg, uint64_t base) {
        #pragma unroll
        for (int ch = 0; ch < 8; ++ch)
            asm volatile("global_load_dwordx4 %0, %1, %2 sc0"
                         : "=v"(stg[ch])
                         : "v"(voff), "s"(base + (uint64_t)(ch * 4096)));
    };
    auto lwrite = [&](const i32x4* stg, int reg) {
        #pragma unroll
        for (int ch = 0; ch < 8; ++ch) hsm4[reg * 2048 + ch * 256 + tid] = stg[ch];
    };
    auto mchunk = [&](int reg, int kbase) {
        const bf16x8* hls = (const bf16x8*)(hsm4 + reg * 2048);
        #pragma unroll
        for (int kt = 0; kt < 16; ++kt) {
            acc0 = mfma(hls[kt * 128 + l],      wreg[kbase + kt], acc0);
            acc1 = mfma(hls[kt * 128 + 64 + l], wreg[kbase + kt], acc1);
        }
    };

    #pragma unroll 1
    for (int t = 0; t < NT; ++t) {
        acc0 = (f32x16){};
        acc1 = (f32x16){};

        // ---- xm part: plain cached loads, independent of the flag ----
        const bf16x8* __restrict__ xp = XMv + (size_t)t * 16384 + bi * 2048 + l;
        #pragma unroll
        for (int kt = 0; kt < 16; ++kt) {
            bf16x8 bfr = WPx[kt * 64];
            acc0 = mfma(xp[kt * 128],      bfr, acc0);
            acc1 = mfma(xp[kt * 128 + 64], bfr, acc1);
        }

        // ---- wait for h(t-1) from the 32-WG group ----
        if (t > 0 && tid == 0) {
            const int target = 32 * t;
            if constexpr (BAL) {
                while (__hip_atomic_fetch_add(flag, 0, __ATOMIC_RELAXED,
                                              __HIP_MEMORY_SCOPE_WORKGROUP) < target)
                    __builtin_amdgcn_s_sleep(1);
            } else {
                while (__hip_atomic_load(flag, __ATOMIC_RELAXED,
                                         __HIP_MEMORY_SCOPE_AGENT) < target)
                    __builtin_amdgcn_s_sleep(2);
            }
        }
        __syncthreads();   // (c)

        if (t > 0) {
            __asm__ volatile("" ::: "memory");
            const char* hb = (const char*)((t & 1) ? hA : hB) + (size_t)bi * 131072;

            if constexpr (BAL) {
                uint64_t hb64 = (uint64_t)(uintptr_t)hb;
                i32x4 s0[8], s1[8];
                issue(s0, hb64);             // c0
                issue(s1, hb64 + 32768);     // c1
                asm volatile("s_waitcnt vmcnt(8)" ::: "memory");   // c0 arrived
                lwrite(s0, 0); __syncthreads();
                issue(s0, hb64 + 65536);     // c2
                mchunk(0, 0);
                asm volatile("s_waitcnt vmcnt(8)" ::: "memory");   // c1 arrived
                lwrite(s1, 1); __syncthreads();
                issue(s1, hb64 + 98304);     // c3
                mchunk(1, 16);
                asm volatile("s_waitcnt vmcnt(8)" ::: "memory");   // c2 arrived
                lwrite(s0, 0); __syncthreads();
                mchunk(0, 32);
                asm volatile("s_waitcnt vmcnt(0)" ::: "memory");   // c3 arrived
                lwrite(s1, 1); __syncthreads();
                mchunk(1, 48);
                __syncthreads();   // all waves done reading before exch overlay
            } else {
                const unsigned long long* __restrict__ hr =
                    (const unsigned long long*)hb + tid;
                unsigned long long stg[16];
                #pragma unroll
                for (int ch = 0; ch < 16; ++ch)
                    stg[ch] = __hip_atomic_load(hr + ch * 256, __ATOMIC_RELAXED,
                                                __HIP_MEMORY_SCOPE_AGENT);
                #pragma unroll
                for (int ch = 0; ch < 16; ++ch) hsm[ch * 256 + tid] = stg[ch];
                __syncthreads();
                #pragma unroll
                for (int ci = 0; ci < 4; ++ci) {
                    if (ci < 3) {
                        #pragma unroll
                        for (int ch = 0; ch < 16; ++ch)
                            stg[ch] = __hip_atomic_load(hr + (ci + 1) * 4096 + ch * 256,
                                                        __ATOMIC_RELAXED,
                                                        __HIP_MEMORY_SCOPE_AGENT);
                    }
                    mchunk(ci & 1, ci * 16);
                    if (ci < 3) {
                        unsigned long long* __restrict__ dst = hsm + ((ci + 1) & 1) * 4096;
                        #pragma unroll
                        for (int ch = 0; ch < 16; ++ch) dst[ch * 256 + tid] = stg[ch];
                    }
                    __syncthreads();
                }
            }
        }

        // ---- gate transpose through per-wave LDS ----
        const int jj = c >> 2;
        const int wb = w * 2560;
        #pragma unroll
        for (int ri = 0; ri < 16; ++ri) {
            int r0 = (ri & 3) + 8 * (ri >> 2) + 4 * (l >> 5);
            exch[wb + (r0 * 8 + jj) * 5 + gate]        = acc0[ri] + bias;
            exch[wb + ((r0 + 32) * 8 + jj) * 5 + gate] = acc1[ri] + bias;
        }

        unsigned int* __restrict__ hw =
            ((t & 1) ? hB : hA) + (size_t)bi * 32768 + (jg >> 1) * 512 + p;
        float pr[4];
        #pragma unroll
        for (int k = 0; k < 4; ++k) {
            int r = rl + 16 * k;
            int f0 = wb + (r * 8 + 2 * p) * 5;
            float ia = sigmoidf_(exch[f0 + 0]);
            float fa = sigmoidf_(exch[f0 + 1]);
            float ga = tanhf_(exch[f0 + 2]);
            float oa = sigmoidf_(exch[f0 + 3]);
            float ib = sigmoidf_(exch[f0 + 5]);
            float fb = sigmoidf_(exch[f0 + 6]);
            float gb = tanhf_(exch[f0 + 7]);
            float ob = sigmoidf_(exch[f0 + 8]);
            float c0 = fa * creg[2 * k] + ia * ga;     creg[2 * k] = c0;
            float c1 = fb * creg[2 * k + 1] + ib * gb; creg[2 * k + 1] = c1;
            float h0 = oa * tanhf_(c0);
            float h1 = ob * tanhf_(c1);
            unsigned int pk = (unsigned int)f2bf(h0) | ((unsigned int)f2bf(h1) << 16);
            int a = r >> 5;
            int flane = ((jg & 1) << 5) | (r & 31);
            if constexpr (BAL)
                hw[a * 256 + flane * 4] = pk;          // write-through L1 -> XCD L2
            else
                __hip_atomic_store(&hw[a * 256 + flane * 4], pk, __ATOMIC_RELAXED,
                                   __HIP_MEMORY_SCOPE_AGENT);
            pr[k] = h0 * wl0 + h1 * wl1;
        }

        #pragma unroll
        for (int k = 0; k < 4; ++k) {
            float v = pr[k];
            v += __shfl_xor(v, 1);
            v += __shfl_xor(v, 2);
            if (p == 0) outred[w * 64 + rl + 16 * k] = v;
        }

        // drain h stores to the coherence point before signaling
        asm volatile("s_waitcnt vmcnt(0)" ::: "memory");
        __syncthreads();   // (b)

        if (tid < 64) {
            float s = outred[tid] + outred[64 + tid] + outred[128 + tid] + outred[192 + tid];
            if (OPart)
                OPart[((size_t)(t * 8 + bi) * 32 + wgJ) * 64 + tid] = s;
            else
                atomicAdd(out + (size_t)t * NGRID + bi * 64 + tid, s);
        }
        if (tid == 0) {
            __asm__ volatile("" ::: "memory");
            if constexpr (BAL)
                __hip_atomic_fetch_add(flag, 1, __ATOMIC_RELAXED,
                                       __HIP_MEMORY_SCOPE_WORKGROUP);
            else
                __hip_atomic_fetch_add(flag, 1, __ATOMIC_RELAXED,
                                       __HIP_MEMORY_SCOPE_AGENT);
        }
    }
}

__global__ __launch_bounds__(256, 1)
void lstm_persist_kernel(const unsigned short* __restrict__ WPg,
                         const unsigned short* __restrict__ XMg,
                         unsigned int* __restrict__ hA,
                         unsigned int* __restrict__ hB,
                         const float* __restrict__ b_ih,
                         const float* __restrict__ b_hh,
                         const float* __restrict__ W_lin,
                         float* __restrict__ out,
                         float* __restrict__ OPart,
                         int* __restrict__ ctr)
{
    __shared__ i32x4 hsm4[4096];   // 64 KB
    __shared__ int setup_sh[3];
    const int tid = threadIdx.x;

    // one-time self-organization by physical XCD
    if (tid == 0) {
        uint32_t xcc;
        asm volatile("s_getreg_b32 %0, hwreg(HW_REG_XCC_ID)" : "=s"(xcc));
        xcc &= 7;
        int slot = __hip_atomic_fetch_add(&ctr[xcc], 1, __ATOMIC_RELAXED,
                                          __HIP_MEMORY_SCOPE_AGENT);
        asm volatile("s_waitcnt vmcnt(0)" ::: "memory");  // claim visible before arrive
        __hip_atomic_fetch_add(&ctr[8], 1, __ATOMIC_RELAXED,
                               __HIP_MEMORY_SCOPE_AGENT);
        while (__hip_atomic_load(&ctr[8], __ATOMIC_RELAXED,
                                 __HIP_MEMORY_SCOPE_AGENT) < 256)
            __builtin_amdgcn_s_sleep(1);
        int bal = 1;
        #pragma unroll
        for (int k = 0; k < 8; ++k)
            bal &= (__hip_atomic_load(&ctr[k], __ATOMIC_RELAXED,
                                      __HIP_MEMORY_SCOPE_AGENT) == 32);
        if (bal && slot < 32) {
            setup_sh[0] = 1; setup_sh[1] = (int)xcc; setup_sh[2] = slot;
        } else {
            setup_sh[0] = 0; setup_sh[1] = blockIdx.x & 7; setup_sh[2] = blockIdx.x >> 3;
        }
    }
    __syncthreads();
    const int bal = setup_sh[0];
    const int bi  = setup_sh[1];
    const int wgJ = setup_sh[2];
    int* flag = ctr + 256 + bi * 32;   // 128B-separated per group

    if (bal)
        lstm_loop<true>(tid, bi, wgJ, WPg, XMg, hA, hB, b_ih, b_hh, W_lin,
                        out, OPart, flag, hsm4);
    else
        lstm_loop<false>(tid, bi, wgJ, WPg, XMg, hA, hB, b_ih, b_hh, W_lin,
                         out, OPart, flag, hsm4);
}

// ---------------- launch ----------------
extern "C" void kernel_launch(void* const* d_in, const int* in_sizes, int n_in,
                              void* d_out, int out_size, void* d_ws, size_t ws_size,
                              hipStream_t stream)
{
    const float* x     = (const float*)d_in[0];
    const float* maskX = (const float*)d_in[1];
    const float* W_ih  = (const float*)d_in[2];
    const float* W_hh  = (const float*)d_in[3];
    const float* b_ih  = (const float*)d_in[4];
    const float* b_hh  = (const float*)d_in[5];
    const float* W_lin = (const float*)d_in[6];
    const float* b_lin = (const float*)d_in[7];
    float* out = (float*)d_out;

    char* ws = (char*)d_ws;
    const size_t WP_B  = 128ull * 80 * 512 * 2;          // 10,485,760
    const size_t XM_B  = (size_t)NT * 16384 * 8 * 2;     // 95,682,560
    const size_t H_B   = (size_t)NGRID * HID * 2;        // 1,048,576
    const size_t CTR_B = 4096;
    const size_t OP_B  = (size_t)NT * 8 * 32 * 64 * 4;   // 23,920,640

    unsigned short* WP = (unsigned short*)ws;
    unsigned short* XM = (unsigned short*)(ws + WP_B);
    unsigned int* hA   = (unsigned int*)(ws + WP_B + XM_B);
    unsigned int* hB   = (unsigned int*)(ws + WP_B + XM_B + H_B);
    int* ctr           = (int*)(ws + WP_B + XM_B + 2 * H_B);
    float* OPart       = (float*)(ws + WP_B + XM_B + 2 * H_B + CTR_B);

    const size_t need = WP_B + XM_B + 2 * H_B + CTR_B + OP_B;
    const bool use_part = (ws_size >= need);
    if (!use_part) OPart = nullptr;

    init_kernel<<<(NT * NGRID + 255) / 256, 256, 0, stream>>>(out, b_lin, ctr,
                                                              use_part ? 0 : 1);
    pack_w_kernel<<<(128 * 80 * 64 + 255) / 256, 256, 0, stream>>>(W_ih, W_hh, WP);
    size_t nxm = (size_t)NT * 16384;
    pack_xm_kernel<<<(int)((nxm + 255) / 256), 256, 0, stream>>>(x, maskX, XM);

    lstm_persist_kernel<<<256, 256, 0, stream>>>(WP, XM, hA, hB,
                                                 b_ih, b_hh, W_lin, out, OPart, ctr);
    if (use_part)
        reduce_out_kernel<<<(NT * NGRID + 255) / 256, 256, 0, stream>>>(OPart, b_lin, out);
}